// Round 1
// baseline (1436.682 us; speedup 1.0000x reference)
//
#include <hip/hip_runtime.h>
#include <hip/hip_bf16.h>

#define SS 256
#define BB 512
#define II 64
#define HH 128
#define DD 32
#define G3 384   // 3*H

// ---------------------------------------------------------------------------
// K1: masked per-channel sum / sumsq (f64 accumulators in workspace)
// ---------------------------------------------------------------------------
__global__ __launch_bounds__(256) void stats_kernel(
    const float* __restrict__ v, const int* __restrict__ lengths,
    double* __restrict__ acc_sum, double* __restrict__ acc_sq,
    int C, int rows, int rows_per_block)
{
    __shared__ float red_s[256];
    __shared__ float red_q[256];
    const int tid = threadIdx.x;
    const int c   = tid & (C - 1);
    const int rg  = tid / C;
    const int rpg = 256 / C;
    const int r0  = blockIdx.x * rows_per_block;
    const int r1  = min(rows, r0 + rows_per_block);
    float s = 0.f, q = 0.f;
    for (int r = r0 + rg; r < r1; r += rpg) {
        const int b  = r & (BB - 1);
        const int si = r >> 9;                 // r / B
        if (si < lengths[b]) {
            const float xv = v[r * C + c];
            s += xv;
            q  = fmaf(xv, xv, q);
        }
    }
    red_s[tid] = s; red_q[tid] = q;
    __syncthreads();
    if (rg == 0) {
        for (int g = 1; g < rpg; ++g) { s += red_s[c + g * C]; q += red_q[c + g * C]; }
        atomicAdd(&acc_sum[c], (double)s);
        atomicAdd(&acc_sq[c],  (double)q);
    }
}

// ---------------------------------------------------------------------------
// K2: finalize -> folded BN coefficients  xn = x*a + c
// der layout: [0:64]=a_x [64:128]=c_x [128:160]=a_d [160:192]=c_d
// ---------------------------------------------------------------------------
__global__ __launch_bounds__(128) void finalize_kernel(
    const int* __restrict__ lengths, const double* __restrict__ acc,
    const float* __restrict__ bn_g, const float* __restrict__ bn_b,
    const float* __restrict__ bnd_g, const float* __restrict__ bnd_b,
    float* __restrict__ der)
{
    __shared__ int redc[128];
    __shared__ double s_inv;
    const int tid = threadIdx.x;
    int cs = 0;
    for (int i = tid; i < BB; i += 128) cs += lengths[i];
    redc[tid] = cs;
    __syncthreads();
    if (tid == 0) {
        int tot = 0;
        for (int i = 0; i < 128; ++i) tot += redc[i];
        s_inv = 1.0 / (double)tot;
    }
    __syncthreads();
    const double inv = s_inv;
    if (tid < 64) {
        const double mu  = acc[tid] * inv;
        const double var = acc[64 + tid] * inv - mu * mu;
        const float  rs  = rsqrtf((float)(var + 1e-5));
        const float  a   = rs * bn_g[tid];
        der[tid]      = a;
        der[64 + tid] = bn_b[tid] - (float)mu * a;
    } else if (tid < 96) {
        const int i = tid - 64;
        const double mu  = acc[128 + i] * inv;
        const double var = acc[160 + i] * inv - mu * mu;
        const float  rs  = rsqrtf((float)(var + 1e-5));
        const float  a   = rs * bnd_g[i];
        der[128 + i] = a;
        der[160 + i] = bnd_b[i] - (float)mu * a;
    }
}

// ---------------------------------------------------------------------------
// K3: GRU recurrence. 256 blocks x 384 threads; block handles 2 batch rows.
// Thread j owns gate-row j: Whh[j][0:128] + Wih[j][0:64] in VGPRs.
// h kept in LDS (f32); gi computed on the fly (BN folded into x load).
// ys written into d_out (padded steps -> 0); h_last appended after ys.
// ---------------------------------------------------------------------------
__global__ __launch_bounds__(384, 1) void gru_kernel(
    const float* __restrict__ x, const int* __restrict__ lengths,
    const float* __restrict__ Wih, const float* __restrict__ Whh,
    const float* __restrict__ bih, const float* __restrict__ bhh,
    const float* __restrict__ der,
    float* __restrict__ ys, float* __restrict__ hlast)
{
    __shared__ __align__(16) float h0[HH];
    __shared__ __align__(16) float h1[HH];
    __shared__ __align__(16) float xr0[II];
    __shared__ __align__(16) float xr1[II];
    __shared__ float pr[2][HH], pz[2][HH], phn[2][HH], pin[2][HH];
    __shared__ float a_x_s[II], c_x_s[II];

    const int tid = threadIdx.x;
    const int b0 = blockIdx.x * 2, b1 = b0 + 1;

    float wh[HH];
    float wi[II];
#pragma unroll
    for (int k = 0; k < HH; k += 4)
        *(float4*)&wh[k] = *(const float4*)&Whh[tid * HH + k];
#pragma unroll
    for (int k = 0; k < II; k += 4)
        *(float4*)&wi[k] = *(const float4*)&Wih[tid * II + k];
    const float bi = bih[tid];
    const float bh = bhh[tid];

    if (tid < II) { a_x_s[tid] = der[tid]; c_x_s[tid] = der[64 + tid]; }
    if (tid < HH) { h0[tid] = 0.f; h1[tid] = 0.f; }
    const int len0 = lengths[b0], len1 = lengths[b1];
    __syncthreads();

    for (int t = 0; t < SS; ++t) {
        // stage normalized x rows
        if (tid < II) {
            xr0[tid] = fmaf(x[(t * BB + b0) * II + tid], a_x_s[tid], c_x_s[tid]);
        } else if (tid < 2 * II) {
            const int i = tid - II;
            xr1[i] = fmaf(x[(t * BB + b1) * II + i], a_x_s[i], c_x_s[i]);
        }
        __syncthreads();

        float g0 = 0.f, g1 = 0.f, e0 = 0.f, e1 = 0.f;
#pragma unroll
        for (int k = 0; k < HH; k += 4) {
            const float4 hv0 = *(const float4*)&h0[k];
            const float4 hv1 = *(const float4*)&h1[k];
            g0 = fmaf(wh[k], hv0.x, g0); g0 = fmaf(wh[k+1], hv0.y, g0);
            g0 = fmaf(wh[k+2], hv0.z, g0); g0 = fmaf(wh[k+3], hv0.w, g0);
            g1 = fmaf(wh[k], hv1.x, g1); g1 = fmaf(wh[k+1], hv1.y, g1);
            g1 = fmaf(wh[k+2], hv1.z, g1); g1 = fmaf(wh[k+3], hv1.w, g1);
        }
#pragma unroll
        for (int k = 0; k < II; k += 4) {
            const float4 xv0 = *(const float4*)&xr0[k];
            const float4 xv1 = *(const float4*)&xr1[k];
            e0 = fmaf(wi[k], xv0.x, e0); e0 = fmaf(wi[k+1], xv0.y, e0);
            e0 = fmaf(wi[k+2], xv0.z, e0); e0 = fmaf(wi[k+3], xv0.w, e0);
            e1 = fmaf(wi[k], xv1.x, e1); e1 = fmaf(wi[k+1], xv1.y, e1);
            e1 = fmaf(wi[k+2], xv1.z, e1); e1 = fmaf(wi[k+3], xv1.w, e1);
        }

        if (tid < HH) {
            pr[0][tid] = g0 + e0 + bi + bh;
            pr[1][tid] = g1 + e1 + bi + bh;
        } else if (tid < 2 * HH) {
            const int u = tid - HH;
            pz[0][u] = g0 + e0 + bi + bh;
            pz[1][u] = g1 + e1 + bi + bh;
        } else {
            const int u = tid - 2 * HH;
            phn[0][u] = g0 + bh;  phn[1][u] = g1 + bh;
            pin[0][u] = e0 + bi;  pin[1][u] = e1 + bi;
        }
        __syncthreads();

        if (tid < 2 * HH) {
            const int u  = tid & (HH - 1);
            const int bb = tid >> 7;
            const float hp = bb ? h1[u] : h0[u];
            const float r  = 1.f / (1.f + __expf(-pr[bb][u]));
            const float z  = 1.f / (1.f + __expf(-pz[bb][u]));
            const float n  = tanhf(pin[bb][u] + r * phn[bb][u]);
            const float hnew = (1.f - z) * n + z * hp;
            const int len = bb ? len1 : len0;
            const bool valid = (t < len);
            const float hv = valid ? hnew : hp;
            if (bb) h1[u] = hv; else h0[u] = hv;
            ys[(t * BB + (bb ? b1 : b0)) * HH + u] = valid ? hnew : 0.f;
        }
        __syncthreads();
    }

    if (tid < 2 * HH) {
        const int u  = tid & (HH - 1);
        const int bb = tid >> 7;
        hlast[(bb ? b1 : b0) * HH + u] = bb ? h1[u] : h0[u];
    }
}

// ---------------------------------------------------------------------------
// K4a: MLP layer 1 (in-place on d_out). 128 threads = 128 output units.
// Thread u holds W1 row u (160 regs); z0 = [y(128) | xdn(32)] staged in LDS.
// ---------------------------------------------------------------------------
__global__ __launch_bounds__(128) void mlp1_kernel(
    const float* __restrict__ xd, const float* __restrict__ W1,
    const float* __restrict__ b1v, const float* __restrict__ der,
    float* __restrict__ io, int tokens_per_block)
{
    __shared__ __align__(16) float z0[HH + DD];
    const int tid = threadIdx.x;
    float w[HH + DD];
#pragma unroll
    for (int k = 0; k < HH + DD; k += 4)
        *(float4*)&w[k] = *(const float4*)&W1[tid * (HH + DD) + k];
    const float bias = b1v[tid];
    const float ad = (tid < DD) ? der[128 + tid] : 0.f;
    const float cd = (tid < DD) ? der[160 + tid] : 0.f;

    const int tok0 = blockIdx.x * tokens_per_block;
    for (int tk = 0; tk < tokens_per_block; ++tk) {
        const int tok = tok0 + tk;
        z0[tid] = io[tok * HH + tid];
        if (tid < DD) z0[HH + tid] = fmaf(xd[tok * DD + tid], ad, cd);
        __syncthreads();
        float acc = bias;
#pragma unroll
        for (int k = 0; k < HH + DD; k += 4) {
            const float4 zv = *(const float4*)&z0[k];
            acc = fmaf(w[k], zv.x, acc);   acc = fmaf(w[k+1], zv.y, acc);
            acc = fmaf(w[k+2], zv.z, acc); acc = fmaf(w[k+3], zv.w, acc);
        }
        __syncthreads();
        io[tok * HH + tid] = fmaxf(acc, 0.f);
    }
}

// ---------------------------------------------------------------------------
// K4b/c: MLP layers 2 and 3 (in-place on d_out); layer 3 applies the mask.
// ---------------------------------------------------------------------------
__global__ __launch_bounds__(128) void mlpN_kernel(
    const float* __restrict__ W, const float* __restrict__ bv,
    const int* __restrict__ lengths, float* __restrict__ io,
    int tokens_per_block, int apply_mask)
{
    __shared__ __align__(16) float zin[HH];
    const int tid = threadIdx.x;
    float w[HH];
#pragma unroll
    for (int k = 0; k < HH; k += 4)
        *(float4*)&w[k] = *(const float4*)&W[tid * HH + k];
    const float bias = bv[tid];

    const int tok0 = blockIdx.x * tokens_per_block;
    for (int tk = 0; tk < tokens_per_block; ++tk) {
        const int tok = tok0 + tk;
        zin[tid] = io[tok * HH + tid];
        __syncthreads();
        float acc = bias;
#pragma unroll
        for (int k = 0; k < HH; k += 4) {
            const float4 zv = *(const float4*)&zin[k];
            acc = fmaf(w[k], zv.x, acc);   acc = fmaf(w[k+1], zv.y, acc);
            acc = fmaf(w[k+2], zv.z, acc); acc = fmaf(w[k+3], zv.w, acc);
        }
        float res = fmaxf(acc, 0.f);
        if (apply_mask) {
            const int t = tok >> 9;
            const int b = tok & (BB - 1);
            if (t >= lengths[b]) res = 0.f;
        }
        __syncthreads();
        io[tok * HH + tid] = res;
    }
}

// ---------------------------------------------------------------------------
extern "C" void kernel_launch(void* const* d_in, const int* in_sizes, int n_in,
                              void* d_out, int out_size, void* d_ws, size_t ws_size,
                              hipStream_t stream)
{
    (void)in_sizes; (void)n_in; (void)out_size; (void)ws_size;
    const float* x     = (const float*)d_in[0];
    const float* xd    = (const float*)d_in[1];
    const int*   lens  = (const int*)d_in[2];
    const float* bn_g  = (const float*)d_in[3];
    const float* bn_b  = (const float*)d_in[4];
    const float* bnd_g = (const float*)d_in[5];
    const float* bnd_b = (const float*)d_in[6];
    const float* Wih   = (const float*)d_in[7];
    const float* Whh   = (const float*)d_in[8];
    const float* bih   = (const float*)d_in[9];
    const float* bhh   = (const float*)d_in[10];
    // d_in[11], d_in[12]: attn_W, attn_b — softmax over size-1 axis == identity
    const float* W1    = (const float*)d_in[13];
    const float* b1    = (const float*)d_in[14];
    const float* W2    = (const float*)d_in[15];
    const float* b2    = (const float*)d_in[16];
    const float* W3    = (const float*)d_in[17];
    const float* b3    = (const float*)d_in[18];

    float* out   = (float*)d_out;
    float* hlast = out + (size_t)SS * BB * HH;

    double* acc = (double*)d_ws;                       // 192 doubles
    float*  der = (float*)((char*)d_ws + 2048);        // 192 floats

    hipMemsetAsync(d_ws, 0, 2048, stream);

    const int rows = SS * BB;
    stats_kernel<<<256, 256, 0, stream>>>(x,  lens, acc,       acc + 64,  II, rows, rows / 256);
    stats_kernel<<<256, 256, 0, stream>>>(xd, lens, acc + 128, acc + 160, DD, rows, rows / 256);
    finalize_kernel<<<1, 128, 0, stream>>>(lens, acc, bn_g, bn_b, bnd_g, bnd_b, der);

    gru_kernel<<<BB / 2, 384, 0, stream>>>(x, lens, Wih, Whh, bih, bhh, der, out, hlast);

    const int tokens = SS * BB;           // 131072
    const int tpb = 128;
    mlp1_kernel<<<tokens / tpb, 128, 0, stream>>>(xd, W1, b1, der, out, tpb);
    mlpN_kernel<<<tokens / tpb, 128, 0, stream>>>(W2, b2, lens, out, tpb, 0);
    mlpN_kernel<<<tokens / tpb, 128, 0, stream>>>(W3, b3, lens, out, tpb, 1);
}

// Round 2
// 1380.094 us; speedup vs baseline: 1.0410x; 1.0410x over previous
//
#include <hip/hip_runtime.h>
#include <hip/hip_bf16.h>

#define SS 256
#define BB 512
#define II 64
#define HH 128
#define DD 32
#define G3 384   // 3*H

// ---------------------------------------------------------------------------
// K1: masked per-channel sum / sumsq (f64 accumulators in workspace)
// ---------------------------------------------------------------------------
__global__ __launch_bounds__(256) void stats_kernel(
    const float* __restrict__ v, const int* __restrict__ lengths,
    double* __restrict__ acc_sum, double* __restrict__ acc_sq,
    int C, int rows, int rows_per_block)
{
    __shared__ float red_s[256];
    __shared__ float red_q[256];
    const int tid = threadIdx.x;
    const int c   = tid & (C - 1);
    const int rg  = tid / C;
    const int rpg = 256 / C;
    const int r0  = blockIdx.x * rows_per_block;
    const int r1  = min(rows, r0 + rows_per_block);
    float s = 0.f, q = 0.f;
    for (int r = r0 + rg; r < r1; r += rpg) {
        const int b  = r & (BB - 1);
        const int si = r >> 9;                 // r / B
        if (si < lengths[b]) {
            const float xv = v[r * C + c];
            s += xv;
            q  = fmaf(xv, xv, q);
        }
    }
    red_s[tid] = s; red_q[tid] = q;
    __syncthreads();
    if (rg == 0) {
        for (int g = 1; g < rpg; ++g) { s += red_s[c + g * C]; q += red_q[c + g * C]; }
        atomicAdd(&acc_sum[c], (double)s);
        atomicAdd(&acc_sq[c],  (double)q);
    }
}

// ---------------------------------------------------------------------------
// K2: finalize -> folded BN coefficients  xn = x*a + c
// der layout: [0:64]=a_x [64:128]=c_x [128:160]=a_d [160:192]=c_d
// ---------------------------------------------------------------------------
__global__ __launch_bounds__(128) void finalize_kernel(
    const int* __restrict__ lengths, const double* __restrict__ acc,
    const float* __restrict__ bn_g, const float* __restrict__ bn_b,
    const float* __restrict__ bnd_g, const float* __restrict__ bnd_b,
    float* __restrict__ der)
{
    __shared__ int redc[128];
    __shared__ double s_inv;
    const int tid = threadIdx.x;
    int cs = 0;
    for (int i = tid; i < BB; i += 128) cs += lengths[i];
    redc[tid] = cs;
    __syncthreads();
    if (tid == 0) {
        int tot = 0;
        for (int i = 0; i < 128; ++i) tot += redc[i];
        s_inv = 1.0 / (double)tot;
    }
    __syncthreads();
    const double inv = s_inv;
    if (tid < 64) {
        const double mu  = acc[tid] * inv;
        const double var = acc[64 + tid] * inv - mu * mu;
        const float  rs  = rsqrtf((float)(var + 1e-5));
        const float  a   = rs * bn_g[tid];
        der[tid]      = a;
        der[64 + tid] = bn_b[tid] - (float)mu * a;
    } else if (tid < 96) {
        const int i = tid - 64;
        const double mu  = acc[128 + i] * inv;
        const double var = acc[160 + i] * inv - mu * mu;
        const float  rs  = rsqrtf((float)(var + 1e-5));
        const float  a   = rs * bnd_g[i];
        der[128 + i] = a;
        der[160 + i] = bnd_b[i] - (float)mu * a;
    }
}

// ---------------------------------------------------------------------------
// K3: GRU recurrence v2. 256 blocks x 768 threads; block = 2 batch rows.
// Thread pair (2r, 2r+1) owns gate-row r: each thread holds HALF the row
// (64 Whh + 32 Wih floats) in VGPRs -> truly register-resident (~130 VGPR,
// under the 170 cap at 3 waves/EU). Partial dots combined via shfl_xor(1).
// x_{t+1} prefetched into registers during step t. 2 barriers per step.
// ---------------------------------------------------------------------------
__global__ __launch_bounds__(768, 3) void gru_kernel(
    const float* __restrict__ x, const int* __restrict__ lengths,
    const float* __restrict__ Wih, const float* __restrict__ Whh,
    const float* __restrict__ bih, const float* __restrict__ bhh,
    const float* __restrict__ der,
    float* __restrict__ ys, float* __restrict__ hlast)
{
    __shared__ __align__(16) float h[2][HH];
    __shared__ __align__(16) float xr[2][II];
    __shared__ float gs[2][G3];   // hidden-part + bhh
    __shared__ float es[2][G3];   // input-part  + bih

    const int tid  = threadIdx.x;
    const int row  = tid >> 1;     // gate row 0..383
    const int half = tid & 1;      // which half of the row
    const int b0   = blockIdx.x * 2;

    float wh[64];
    float wi[32];
    const float* whp = Whh + row * HH + half * 64;
    const float* wip = Wih + row * II + half * 32;
#pragma unroll
    for (int k = 0; k < 64; k += 4) *(float4*)&wh[k] = *(const float4*)&whp[k];
#pragma unroll
    for (int k = 0; k < 32; k += 4) *(float4*)&wi[k] = *(const float4*)&wip[k];
    const float bh = bhh[row];
    const float bi = bih[row];
    const int len0 = lengths[b0], len1 = lengths[b0 + 1];

    // staging threads (tid<32): each loads one float4 of one x row
    const int sb = (tid >> 4) & 1;          // batch row within block
    const int sc = (tid & 15) * 4;          // column
    float4 a4, c4;
    if (tid < 32) {
        a4 = *(const float4*)&der[sc];
        c4 = *(const float4*)&der[64 + sc];
    }
    if (tid < HH) { h[0][tid] = 0.f; h[1][tid] = 0.f; }
    if (tid < 32) {
        const float4 xv = *(const float4*)&x[(0 * BB + b0 + sb) * II + sc];
        float4 xn;
        xn.x = fmaf(xv.x, a4.x, c4.x); xn.y = fmaf(xv.y, a4.y, c4.y);
        xn.z = fmaf(xv.z, a4.z, c4.z); xn.w = fmaf(xv.w, a4.w, c4.w);
        *(float4*)&xr[sb][sc] = xn;
    }
    __syncthreads();

    for (int t = 0; t < SS; ++t) {
        // prefetch x_{t+1} (registers; written to LDS after barrier 1)
        float4 pf;
        if (tid < 32 && t + 1 < SS)
            pf = *(const float4*)&x[((t + 1) * BB + b0 + sb) * II + sc];

        // partial dot products (half a row, both batch rows)
        float g0a = 0.f, g0b = 0.f, g1a = 0.f, g1b = 0.f;
        const float* h0p = &h[0][half * 64];
        const float* h1p = &h[1][half * 64];
#pragma unroll
        for (int k = 0; k < 64; k += 8) {
            const float4 ha0 = *(const float4*)&h0p[k];
            const float4 hb0 = *(const float4*)&h0p[k + 4];
            const float4 ha1 = *(const float4*)&h1p[k];
            const float4 hb1 = *(const float4*)&h1p[k + 4];
            g0a = fmaf(wh[k],     ha0.x, g0a); g0a = fmaf(wh[k + 1], ha0.y, g0a);
            g0a = fmaf(wh[k + 2], ha0.z, g0a); g0a = fmaf(wh[k + 3], ha0.w, g0a);
            g0b = fmaf(wh[k + 4], hb0.x, g0b); g0b = fmaf(wh[k + 5], hb0.y, g0b);
            g0b = fmaf(wh[k + 6], hb0.z, g0b); g0b = fmaf(wh[k + 7], hb0.w, g0b);
            g1a = fmaf(wh[k],     ha1.x, g1a); g1a = fmaf(wh[k + 1], ha1.y, g1a);
            g1a = fmaf(wh[k + 2], ha1.z, g1a); g1a = fmaf(wh[k + 3], ha1.w, g1a);
            g1b = fmaf(wh[k + 4], hb1.x, g1b); g1b = fmaf(wh[k + 5], hb1.y, g1b);
            g1b = fmaf(wh[k + 6], hb1.z, g1b); g1b = fmaf(wh[k + 7], hb1.w, g1b);
        }
        float e0 = 0.f, e1 = 0.f;
        const float* x0p = &xr[0][half * 32];
        const float* x1p = &xr[1][half * 32];
#pragma unroll
        for (int k = 0; k < 32; k += 4) {
            const float4 xa = *(const float4*)&x0p[k];
            const float4 xb = *(const float4*)&x1p[k];
            e0 = fmaf(wi[k],     xa.x, e0); e0 = fmaf(wi[k + 1], xa.y, e0);
            e0 = fmaf(wi[k + 2], xa.z, e0); e0 = fmaf(wi[k + 3], xa.w, e0);
            e1 = fmaf(wi[k],     xb.x, e1); e1 = fmaf(wi[k + 1], xb.y, e1);
            e1 = fmaf(wi[k + 2], xb.z, e1); e1 = fmaf(wi[k + 3], xb.w, e1);
        }
        float g0 = g0a + g0b, g1 = g1a + g1b;

        // combine the two halves of each row (pair = adjacent lanes)
        g0 += __shfl_xor(g0, 1);
        g1 += __shfl_xor(g1, 1);
        e0 += __shfl_xor(e0, 1);
        e1 += __shfl_xor(e1, 1);
        if (!half) {
            gs[0][row] = g0 + bh; gs[1][row] = g1 + bh;
            es[0][row] = e0 + bi; es[1][row] = e1 + bi;
        }
        __syncthreads();

        // activations + h update (256 threads), x_{t+1} -> LDS (32 threads)
        if (tid < 2 * HH) {
            const int u = tid & (HH - 1);
            const int b = tid >> 7;
            const float hp = h[b][u];
            const float r  = 1.f / (1.f + __expf(-(gs[b][u] + es[b][u])));
            const float z  = 1.f / (1.f + __expf(-(gs[b][HH + u] + es[b][HH + u])));
            const float n  = tanhf(es[b][2 * HH + u] + r * gs[b][2 * HH + u]);
            const float hnew = (1.f - z) * n + z * hp;
            const int len = b ? len1 : len0;
            const bool valid = (t < len);
            h[b][u] = valid ? hnew : hp;
            ys[(t * BB + b0 + b) * HH + u] = valid ? hnew : 0.f;
        }
        if (tid < 32 && t + 1 < SS) {
            float4 xn;
            xn.x = fmaf(pf.x, a4.x, c4.x); xn.y = fmaf(pf.y, a4.y, c4.y);
            xn.z = fmaf(pf.z, a4.z, c4.z); xn.w = fmaf(pf.w, a4.w, c4.w);
            *(float4*)&xr[sb][sc] = xn;
        }
        __syncthreads();
    }

    if (tid < 2 * HH) {
        const int u = tid & (HH - 1);
        const int b = tid >> 7;
        hlast[(b0 + b) * HH + u] = h[b][u];
    }
}

// ---------------------------------------------------------------------------
// K4a: MLP layer 1 (in-place on d_out). 128 threads = 128 output units.
// ---------------------------------------------------------------------------
__global__ __launch_bounds__(128) void mlp1_kernel(
    const float* __restrict__ xd, const float* __restrict__ W1,
    const float* __restrict__ b1v, const float* __restrict__ der,
    float* __restrict__ io, int tokens_per_block)
{
    __shared__ __align__(16) float z0[HH + DD];
    const int tid = threadIdx.x;
    float w[HH + DD];
#pragma unroll
    for (int k = 0; k < HH + DD; k += 4)
        *(float4*)&w[k] = *(const float4*)&W1[tid * (HH + DD) + k];
    const float bias = b1v[tid];
    const float ad = (tid < DD) ? der[128 + tid] : 0.f;
    const float cd = (tid < DD) ? der[160 + tid] : 0.f;

    const int tok0 = blockIdx.x * tokens_per_block;
    for (int tk = 0; tk < tokens_per_block; ++tk) {
        const int tok = tok0 + tk;
        z0[tid] = io[tok * HH + tid];
        if (tid < DD) z0[HH + tid] = fmaf(xd[tok * DD + tid], ad, cd);
        __syncthreads();
        float acc = bias;
#pragma unroll
        for (int k = 0; k < HH + DD; k += 4) {
            const float4 zv = *(const float4*)&z0[k];
            acc = fmaf(w[k], zv.x, acc);   acc = fmaf(w[k+1], zv.y, acc);
            acc = fmaf(w[k+2], zv.z, acc); acc = fmaf(w[k+3], zv.w, acc);
        }
        __syncthreads();
        io[tok * HH + tid] = fmaxf(acc, 0.f);
    }
}

// ---------------------------------------------------------------------------
// K4b/c: MLP layers 2 and 3 (in-place on d_out); layer 3 applies the mask.
// ---------------------------------------------------------------------------
__global__ __launch_bounds__(128) void mlpN_kernel(
    const float* __restrict__ W, const float* __restrict__ bv,
    const int* __restrict__ lengths, float* __restrict__ io,
    int tokens_per_block, int apply_mask)
{
    __shared__ __align__(16) float zin[HH];
    const int tid = threadIdx.x;
    float w[HH];
#pragma unroll
    for (int k = 0; k < HH; k += 4)
        *(float4*)&w[k] = *(const float4*)&W[tid * HH + k];
    const float bias = bv[tid];

    const int tok0 = blockIdx.x * tokens_per_block;
    for (int tk = 0; tk < tokens_per_block; ++tk) {
        const int tok = tok0 + tk;
        zin[tid] = io[tok * HH + tid];
        __syncthreads();
        float acc = bias;
#pragma unroll
        for (int k = 0; k < HH; k += 4) {
            const float4 zv = *(const float4*)&zin[k];
            acc = fmaf(w[k], zv.x, acc);   acc = fmaf(w[k+1], zv.y, acc);
            acc = fmaf(w[k+2], zv.z, acc); acc = fmaf(w[k+3], zv.w, acc);
        }
        float res = fmaxf(acc, 0.f);
        if (apply_mask) {
            const int t = tok >> 9;
            const int b = tok & (BB - 1);
            if (t >= lengths[b]) res = 0.f;
        }
        __syncthreads();
        io[tok * HH + tid] = res;
    }
}

// ---------------------------------------------------------------------------
extern "C" void kernel_launch(void* const* d_in, const int* in_sizes, int n_in,
                              void* d_out, int out_size, void* d_ws, size_t ws_size,
                              hipStream_t stream)
{
    (void)in_sizes; (void)n_in; (void)out_size; (void)ws_size;
    const float* x     = (const float*)d_in[0];
    const float* xd    = (const float*)d_in[1];
    const int*   lens  = (const int*)d_in[2];
    const float* bn_g  = (const float*)d_in[3];
    const float* bn_b  = (const float*)d_in[4];
    const float* bnd_g = (const float*)d_in[5];
    const float* bnd_b = (const float*)d_in[6];
    const float* Wih   = (const float*)d_in[7];
    const float* Whh   = (const float*)d_in[8];
    const float* bih   = (const float*)d_in[9];
    const float* bhh   = (const float*)d_in[10];
    // d_in[11], d_in[12]: attn_W, attn_b — softmax over size-1 axis == identity
    const float* W1    = (const float*)d_in[13];
    const float* b1    = (const float*)d_in[14];
    const float* W2    = (const float*)d_in[15];
    const float* b2    = (const float*)d_in[16];
    const float* W3    = (const float*)d_in[17];
    const float* b3    = (const float*)d_in[18];

    float* out   = (float*)d_out;
    float* hlast = out + (size_t)SS * BB * HH;

    double* acc = (double*)d_ws;                       // 192 doubles
    float*  der = (float*)((char*)d_ws + 2048);        // 192 floats

    hipMemsetAsync(d_ws, 0, 2048, stream);

    const int rows = SS * BB;
    stats_kernel<<<256, 256, 0, stream>>>(x,  lens, acc,       acc + 64,  II, rows, rows / 256);
    stats_kernel<<<256, 256, 0, stream>>>(xd, lens, acc + 128, acc + 160, DD, rows, rows / 256);
    finalize_kernel<<<1, 128, 0, stream>>>(lens, acc, bn_g, bn_b, bnd_g, bnd_b, der);

    gru_kernel<<<BB / 2, 768, 0, stream>>>(x, lens, Wih, Whh, bih, bhh, der, out, hlast);

    const int tokens = SS * BB;           // 131072
    const int tpb = 128;
    mlp1_kernel<<<tokens / tpb, 128, 0, stream>>>(xd, W1, b1, der, out, tpb);
    mlpN_kernel<<<tokens / tpb, 128, 0, stream>>>(W2, b2, lens, out, tpb, 0);
    mlpN_kernel<<<tokens / tpb, 128, 0, stream>>>(W3, b3, lens, out, tpb, 1);
}

// Round 3
// 563.662 us; speedup vs baseline: 2.5488x; 2.4484x over previous
//
#include <hip/hip_runtime.h>
#include <hip/hip_bf16.h>

#define SS 256
#define BB 512
#define II 64
#define HH 128
#define DD 32
#define G3 384   // 3*H

typedef __attribute__((ext_vector_type(8))) short short8;   // 8 bf16 (4 VGPRs)
typedef __attribute__((ext_vector_type(4))) float f32x4;

__device__ __forceinline__ short f2bf(float f) {
    unsigned u = __builtin_bit_cast(unsigned, f);
    u += 0x7FFFu + ((u >> 16) & 1u);            // RNE
    return (short)(u >> 16);
}
__device__ __forceinline__ int pack2bf(float a, float b) {
    return (int)((((unsigned)(unsigned short)f2bf(b)) << 16) |
                  ((unsigned)(unsigned short)f2bf(a)));
}
__device__ __forceinline__ short8 load8bf(const float* p) {
    short8 r;
#pragma unroll
    for (int j = 0; j < 8; ++j) r[j] = f2bf(p[j]);
    return r;
}

// ---------------------------------------------------------------------------
// K1: masked per-channel sum / sumsq (f64 accumulators in workspace)
// ---------------------------------------------------------------------------
__global__ __launch_bounds__(256) void stats_kernel(
    const float* __restrict__ v, const int* __restrict__ lengths,
    double* __restrict__ acc_sum, double* __restrict__ acc_sq,
    int C, int rows, int rows_per_block)
{
    __shared__ float red_s[256];
    __shared__ float red_q[256];
    const int tid = threadIdx.x;
    const int c   = tid & (C - 1);
    const int rg  = tid / C;
    const int rpg = 256 / C;
    const int r0  = blockIdx.x * rows_per_block;
    const int r1  = min(rows, r0 + rows_per_block);
    float s = 0.f, q = 0.f;
    for (int r = r0 + rg; r < r1; r += rpg) {
        const int b  = r & (BB - 1);
        const int si = r >> 9;
        if (si < lengths[b]) {
            const float xv = v[r * C + c];
            s += xv;
            q  = fmaf(xv, xv, q);
        }
    }
    red_s[tid] = s; red_q[tid] = q;
    __syncthreads();
    if (rg == 0) {
        for (int g = 1; g < rpg; ++g) { s += red_s[c + g * C]; q += red_q[c + g * C]; }
        atomicAdd(&acc_sum[c], (double)s);
        atomicAdd(&acc_sq[c],  (double)q);
    }
}

// ---------------------------------------------------------------------------
// K2: finalize -> folded BN coefficients  xn = x*a + c
// der layout: [0:64]=a_x [64:128]=c_x [128:160]=a_d [160:192]=c_d
// ---------------------------------------------------------------------------
__global__ __launch_bounds__(128) void finalize_kernel(
    const int* __restrict__ lengths, const double* __restrict__ acc,
    const float* __restrict__ bn_g, const float* __restrict__ bn_b,
    const float* __restrict__ bnd_g, const float* __restrict__ bnd_b,
    float* __restrict__ der)
{
    __shared__ int redc[128];
    __shared__ double s_inv;
    const int tid = threadIdx.x;
    int cs = 0;
    for (int i = tid; i < BB; i += 128) cs += lengths[i];
    redc[tid] = cs;
    __syncthreads();
    if (tid == 0) {
        int tot = 0;
        for (int i = 0; i < 128; ++i) tot += redc[i];
        s_inv = 1.0 / (double)tot;
    }
    __syncthreads();
    const double inv = s_inv;
    if (tid < 64) {
        const double mu  = acc[tid] * inv;
        const double var = acc[64 + tid] * inv - mu * mu;
        const float  rs  = rsqrtf((float)(var + 1e-5));
        const float  a   = rs * bn_g[tid];
        der[tid]      = a;
        der[64 + tid] = bn_b[tid] - (float)mu * a;
    } else if (tid < 96) {
        const int i = tid - 64;
        const double mu  = acc[128 + i] * inv;
        const double var = acc[160 + i] * inv - mu * mu;
        const float  rs  = rsqrtf((float)(var + 1e-5));
        const float  a   = rs * bnd_g[i];
        der[128 + i] = a;
        der[160 + i] = bnd_b[i] - (float)mu * a;
    }
}

// ---------------------------------------------------------------------------
// K3: MFMA GRU. 32 blocks x 512 threads (8 waves); block = 16 batch rows.
// Per step: gates[16x384] = h[16x128] @ Whh^T + xn[16x64] @ Wih^T  via
// mfma_f32_16x16x32_bf16. Wave w owns gate columns u in [16w,16w+16) for all
// three gates (r-tile w, z-tile 8+w, n-tile 16+w). All weight B-fragments are
// VGPR-resident for the whole kernel (18 frags = 72 VGPR). A-frags (h, xn as
// bf16) come from padded LDS (row stride 136/72 shorts -> 2-way conflicts
// only). Activation is done in registers by the lanes that hold the MFMA
// accumulators; master h state stays f32 in registers (4/lane).
// ---------------------------------------------------------------------------
__global__ __launch_bounds__(512) void gru_kernel(
    const float* __restrict__ x, const int* __restrict__ lengths,
    const float* __restrict__ Wih, const float* __restrict__ Whh,
    const float* __restrict__ bih, const float* __restrict__ bhh,
    const float* __restrict__ der,
    float* __restrict__ ys, float* __restrict__ hlast)
{
    __shared__ __align__(16) short hbf[16 * 136];       // h bf16, +8 pad
    __shared__ __align__(16) short xbf[2][16 * 72];     // xn bf16, +8 pad, dbuf

    const int tid  = threadIdx.x;
    const int w    = tid >> 6;
    const int l    = tid & 63;
    const int col  = l & 15;
    const int quad = l >> 4;
    const int b0   = blockIdx.x * 16;
    const int u    = 16 * w + col;                      // gate unit 0..127

    // ---- weight fragments (persistent in VGPRs) ----
    const int nr = u, nz = HH + u, nn = 2 * HH + u;     // rows of Whh/Wih
    short8 WR[6], WZ[6], WNh[4], WNx[2];
#pragma unroll
    for (int ks = 0; ks < 4; ++ks) {
        WR[ks]  = load8bf(&Whh[nr * HH + ks * 32 + quad * 8]);
        WZ[ks]  = load8bf(&Whh[nz * HH + ks * 32 + quad * 8]);
        WNh[ks] = load8bf(&Whh[nn * HH + ks * 32 + quad * 8]);
    }
#pragma unroll
    for (int ks = 0; ks < 2; ++ks) {
        WR[4 + ks] = load8bf(&Wih[nr * II + ks * 32 + quad * 8]);
        WZ[4 + ks] = load8bf(&Wih[nz * II + ks * 32 + quad * 8]);
        WNx[ks]    = load8bf(&Wih[nn * II + ks * 32 + quad * 8]);
    }
    const float br  = bih[nr] + bhh[nr];
    const float bz  = bih[nz] + bhh[nz];
    const float bnh = bhh[nn];
    const float bnx = bih[nn];

    int lenr[4];
#pragma unroll
    for (int r = 0; r < 4; ++r) lenr[r] = lengths[b0 + quad * 4 + r];

    // x staging: thread -> (srow, sc) covers 16x64 with float2
    const int srow = tid >> 5;
    const int sc   = (tid & 31) * 2;
    const float a0 = der[sc],      a1 = der[sc + 1];
    const float c0 = der[64 + sc], c1 = der[64 + sc + 1];

    // zero h (bf16 buffer) + master state
    for (int i = tid; i < 16 * 136 / 2; i += 512) ((int*)hbf)[i] = 0;
    float hreg[4] = {0.f, 0.f, 0.f, 0.f};

    { // stage xn for t=0
        const float2 xv = *(const float2*)&x[(size_t)(0 * BB + b0 + srow) * II + sc];
        *(int*)&xbf[0][srow * 72 + sc] =
            pack2bf(fmaf(xv.x, a0, c0), fmaf(xv.y, a1, c1));
    }
    __syncthreads();

    int p = 0;
    for (int t = 0; t < SS; ++t) {
        // prefetch x_{t+1} into registers (covers global latency)
        float2 xv;
        if (t + 1 < SS)
            xv = *(const float2*)&x[(size_t)((t + 1) * BB + b0 + srow) * II + sc];

        // A-fragments: lane reads row m=col, k = ks*32 + quad*8 + j
        short8 A[4], AX[2];
#pragma unroll
        for (int ks = 0; ks < 4; ++ks)
            A[ks] = *(const short8*)&hbf[col * 136 + ks * 32 + quad * 8];
#pragma unroll
        for (int ks = 0; ks < 2; ++ks)
            AX[ks] = *(const short8*)&xbf[p][col * 72 + ks * 32 + quad * 8];

        f32x4 ar  = {br,  br,  br,  br };
        f32x4 az  = {bz,  bz,  bz,  bz };
        f32x4 anh = {bnh, bnh, bnh, bnh};
        f32x4 anx = {bnx, bnx, bnx, bnx};
#pragma unroll
        for (int ks = 0; ks < 4; ++ks) {
            ar  = __builtin_amdgcn_mfma_f32_16x16x32_bf16(A[ks], WR[ks],  ar,  0, 0, 0);
            az  = __builtin_amdgcn_mfma_f32_16x16x32_bf16(A[ks], WZ[ks],  az,  0, 0, 0);
            anh = __builtin_amdgcn_mfma_f32_16x16x32_bf16(A[ks], WNh[ks], anh, 0, 0, 0);
        }
#pragma unroll
        for (int ks = 0; ks < 2; ++ks) {
            ar  = __builtin_amdgcn_mfma_f32_16x16x32_bf16(AX[ks], WR[4 + ks], ar,  0, 0, 0);
            az  = __builtin_amdgcn_mfma_f32_16x16x32_bf16(AX[ks], WZ[4 + ks], az,  0, 0, 0);
            anx = __builtin_amdgcn_mfma_f32_16x16x32_bf16(AX[ks], WNx[ks],    anx, 0, 0, 0);
        }
        __syncthreads();   // all reads of hbf/xbf[p] done before rewrites

        // stage xn for t+1 into the other buffer
        if (t + 1 < SS)
            *(int*)&xbf[p ^ 1][srow * 72 + sc] =
                pack2bf(fmaf(xv.x, a0, c0), fmaf(xv.y, a1, c1));

        // activation in registers; lane owns rows 4*quad+r, unit u
#pragma unroll
        for (int r = 0; r < 4; ++r) {
            const float rg = __builtin_amdgcn_rcpf(1.f + __expf(-ar[r]));
            const float zg = __builtin_amdgcn_rcpf(1.f + __expf(-az[r]));
            const float nv = anx[r] + rg * anh[r];
            const float ng = 1.f - 2.f * __builtin_amdgcn_rcpf(1.f + __expf(2.f * nv));
            const float hnew = (1.f - zg) * ng + zg * hreg[r];
            const bool valid = (t < lenr[r]);
            hreg[r] = valid ? hnew : hreg[r];
            const int row = quad * 4 + r;
            hbf[row * 136 + u] = f2bf(hreg[r]);
            ys[((size_t)t * BB + b0 + row) * HH + u] = valid ? hnew : 0.f;
        }
        __syncthreads();
        p ^= 1;
    }

#pragma unroll
    for (int r = 0; r < 4; ++r)
        hlast[(size_t)(b0 + quad * 4 + r) * HH + u] = hreg[r];
}

// ---------------------------------------------------------------------------
// K4: fused 3-layer MLP via MFMA, in-place on d_out. 16-token tiles.
// Wave w owns output units [16w,16w+16) of every layer; W1/W2/W3 fragments
// are VGPR-resident (13 frags). Intermediates round-trip LDS as bf16.
// ---------------------------------------------------------------------------
__global__ __launch_bounds__(512) void mlp_kernel(
    const float* __restrict__ xd, const int* __restrict__ lengths,
    const float* __restrict__ W1, const float* __restrict__ b1v,
    const float* __restrict__ W2, const float* __restrict__ b2v,
    const float* __restrict__ W3, const float* __restrict__ b3v,
    const float* __restrict__ der, float* __restrict__ io, int tiles_per_block)
{
    __shared__ __align__(16) short z0[16 * 168];        // 160 + 8 pad
    __shared__ __align__(16) short dbuf[2][16 * 136];   // 128 + 8 pad

    const int tid  = threadIdx.x;
    const int w    = tid >> 6;
    const int l    = tid & 63;
    const int col  = l & 15;
    const int quad = l >> 4;
    const int u    = 16 * w + col;

    short8 F1[5], F2[4], F3[4];
#pragma unroll
    for (int ks = 0; ks < 5; ++ks) F1[ks] = load8bf(&W1[u * 160 + ks * 32 + quad * 8]);
#pragma unroll
    for (int ks = 0; ks < 4; ++ks) {
        F2[ks] = load8bf(&W2[u * HH + ks * 32 + quad * 8]);
        F3[ks] = load8bf(&W3[u * HH + ks * 32 + quad * 8]);
    }
    const float bb1 = b1v[u], bb2 = b2v[u], bb3 = b3v[u];

    // staging maps
    const int yrow = tid >> 5, yc = (tid & 31) * 4;       // y: float4 per thread
    const int drow = tid >> 4, dc = (tid & 15) * 2;       // xd: first 256 threads
    float ad0 = 0.f, ad1 = 0.f, cd0 = 0.f, cd1 = 0.f;
    if (tid < 256) {
        ad0 = der[128 + dc]; ad1 = der[128 + dc + 1];
        cd0 = der[160 + dc]; cd1 = der[160 + dc + 1];
    }

    for (int it = 0; it < tiles_per_block; ++it) {
        const int tile = blockIdx.x * tiles_per_block + it;
        const int tok0 = tile * 16;

        { // stage z0 = [bf16(y) | bf16(xdn)]
            const float4 yv = *(const float4*)&io[(size_t)(tok0 + yrow) * HH + yc];
            int2 pk;
            pk.x = pack2bf(yv.x, yv.y);
            pk.y = pack2bf(yv.z, yv.w);
            *(int2*)&z0[yrow * 168 + yc] = pk;
            if (tid < 256) {
                const float2 dv = *(const float2*)&xd[(size_t)(tok0 + drow) * DD + dc];
                *(int*)&z0[drow * 168 + HH + dc] =
                    pack2bf(fmaf(dv.x, ad0, cd0), fmaf(dv.y, ad1, cd1));
            }
        }
        __syncthreads();

        // L1: K=160
        f32x4 a1 = {bb1, bb1, bb1, bb1};
#pragma unroll
        for (int ks = 0; ks < 5; ++ks)
            a1 = __builtin_amdgcn_mfma_f32_16x16x32_bf16(
                *(const short8*)&z0[col * 168 + ks * 32 + quad * 8], F1[ks], a1, 0, 0, 0);
#pragma unroll
        for (int r = 0; r < 4; ++r)
            dbuf[0][(quad * 4 + r) * 136 + u] = f2bf(fmaxf(a1[r], 0.f));
        __syncthreads();

        // L2
        f32x4 a2 = {bb2, bb2, bb2, bb2};
#pragma unroll
        for (int ks = 0; ks < 4; ++ks)
            a2 = __builtin_amdgcn_mfma_f32_16x16x32_bf16(
                *(const short8*)&dbuf[0][col * 136 + ks * 32 + quad * 8], F2[ks], a2, 0, 0, 0);
#pragma unroll
        for (int r = 0; r < 4; ++r)
            dbuf[1][(quad * 4 + r) * 136 + u] = f2bf(fmaxf(a2[r], 0.f));
        __syncthreads();

        // L3 + mask + store
        f32x4 a3 = {bb3, bb3, bb3, bb3};
#pragma unroll
        for (int ks = 0; ks < 4; ++ks)
            a3 = __builtin_amdgcn_mfma_f32_16x16x32_bf16(
                *(const short8*)&dbuf[1][col * 136 + ks * 32 + quad * 8], F3[ks], a3, 0, 0, 0);
        const int tI = tok0 >> 9;
        const int bI = tok0 & (BB - 1);
#pragma unroll
        for (int r = 0; r < 4; ++r) {
            const int row = quad * 4 + r;
            float v = fmaxf(a3[r], 0.f);
            if (tI >= lengths[bI + row]) v = 0.f;
            io[(size_t)(tok0 + row) * HH + u] = v;
        }
        __syncthreads();   // protect z0/dbuf for next tile
    }
}

// ---------------------------------------------------------------------------
extern "C" void kernel_launch(void* const* d_in, const int* in_sizes, int n_in,
                              void* d_out, int out_size, void* d_ws, size_t ws_size,
                              hipStream_t stream)
{
    (void)in_sizes; (void)n_in; (void)out_size; (void)ws_size;
    const float* x     = (const float*)d_in[0];
    const float* xd    = (const float*)d_in[1];
    const int*   lens  = (const int*)d_in[2];
    const float* bn_g  = (const float*)d_in[3];
    const float* bn_b  = (const float*)d_in[4];
    const float* bnd_g = (const float*)d_in[5];
    const float* bnd_b = (const float*)d_in[6];
    const float* Wih   = (const float*)d_in[7];
    const float* Whh   = (const float*)d_in[8];
    const float* bih   = (const float*)d_in[9];
    const float* bhh   = (const float*)d_in[10];
    // d_in[11], d_in[12]: attn_W, attn_b — softmax over size-1 axis == identity
    const float* W1    = (const float*)d_in[13];
    const float* b1    = (const float*)d_in[14];
    const float* W2    = (const float*)d_in[15];
    const float* b2    = (const float*)d_in[16];
    const float* W3    = (const float*)d_in[17];
    const float* b3    = (const float*)d_in[18];

    float* out   = (float*)d_out;
    float* hlast = out + (size_t)SS * BB * HH;

    double* acc = (double*)d_ws;                       // 192 doubles
    float*  der = (float*)((char*)d_ws + 2048);        // 192 floats

    hipMemsetAsync(d_ws, 0, 2048, stream);

    const int rows = SS * BB;
    stats_kernel<<<256, 256, 0, stream>>>(x,  lens, acc,       acc + 64,  II, rows, rows / 256);
    stats_kernel<<<256, 256, 0, stream>>>(xd, lens, acc + 128, acc + 160, DD, rows, rows / 256);
    finalize_kernel<<<1, 128, 0, stream>>>(lens, acc, bn_g, bn_b, bnd_g, bnd_b, der);

    gru_kernel<<<BB / 16, 512, 0, stream>>>(x, lens, Wih, Whh, bih, bhh, der, out, hlast);

    const int tiles = SS * BB / 16;   // 8192
    const int tpb   = 8;
    mlp_kernel<<<tiles / tpb, 512, 0, stream>>>(xd, lens, W1, b1, W2, b2, W3, b3,
                                                der, out, tpb);
}